// Round 1
// baseline (158.512 us; speedup 1.0000x reference)
//
#include <hip/hip_runtime.h>

typedef float floatx4 __attribute__((ext_vector_type(4)));
typedef int intx4 __attribute__((ext_vector_type(4)));

#define GN 4096
#define GK 1024
#define BM 256
#define BN 256
#define BK 128          // K-bytes per tile step (two 64-B K-halves)
#define NT (GK / BK)    // 8
#define INVT (1.0f/0.03f)
#define QS 24.0f        // int8 quant scale; dots <= 1024*127^2 < 2^24 (fp32-exact)
#define NTILES 136      // 16*17/2 upper-tri 256-tiles per modality
#define NCROSS 256      // 16*16 cross tiles

static __device__ __forceinline__ int q8(float x) {
    int v = __float2int_rn(x * QS);
    return v < -127 ? -127 : (v > 127 ? 127 : v);
}

// One block per index i: int8-quantize post-row i AND brand-row i, both
// inv-norms (of quantized ints) and the cross-diag int dot, single pass.
// Also zeroes the accumulators + out (replaces hipMemsetAsync dispatches).
__global__ __launch_bounds__(256)
void prep_all(const float* __restrict__ brand, const float* __restrict__ post,
              unsigned char* __restrict__ brandq, unsigned char* __restrict__ postq,
              float* __restrict__ inv_brand, float* __restrict__ inv_post,
              float* __restrict__ dvec, float* __restrict__ accs,
              float* __restrict__ out) {
    const int i = blockIdx.x, tid = threadIdx.x;
    const int wave = tid >> 6, lane = tid & 63;
    __shared__ float swp[4], swb[4], swd[4];

    float4 pv = ((const float4*)(post  + (size_t)i * GK))[tid];
    float4 bv = ((const float4*)(brand + (size_t)i * GK))[tid];
    int p0 = q8(pv.x), p1 = q8(pv.y), p2 = q8(pv.z), p3 = q8(pv.w);
    int b0 = q8(bv.x), b1 = q8(bv.y), b2 = q8(bv.z), b3 = q8(bv.w);
    ((int*)(postq  + (size_t)i * GK))[tid] =
        (p0 & 255) | ((p1 & 255) << 8) | ((p2 & 255) << 16) | ((p3 & 255) << 24);
    ((int*)(brandq + (size_t)i * GK))[tid] =
        (b0 & 255) | ((b1 & 255) << 8) | ((b2 & 255) << 16) | ((b3 & 255) << 24);

    float ssp = (float)(p0 * p0 + p1 * p1 + p2 * p2 + p3 * p3);
    float ssb = (float)(b0 * b0 + b1 * b1 + b2 * b2 + b3 * b3);
    float ssd = (float)(p0 * b0 + p1 * b1 + p2 * b2 + p3 * b3);
    #pragma unroll
    for (int off = 32; off > 0; off >>= 1) {
        ssp += __shfl_down(ssp, off);
        ssb += __shfl_down(ssb, off);
        ssd += __shfl_down(ssd, off);
    }
    if (lane == 0) { swp[wave] = ssp; swb[wave] = ssb; swd[wave] = ssd; }
    __syncthreads();
    if (tid == 0) {
        inv_post[i]  = 1.0f / sqrtf(swp[0] + swp[1] + swp[2] + swp[3]);
        inv_brand[i] = 1.0f / sqrtf(swb[0] + swb[1] + swb[2] + swb[3]);
        dvec[i]      = swd[0] + swd[1] + swd[2] + swd[3];
    } else if (tid == 64) {
        accs[i] = 0.f; accs[GN + i] = 0.f; accs[2 * GN + i] = 0.f; accs[3 * GN + i] = 0.f;
        if (i == 0) out[0] = 0.f;
    }
}

// ---------------------------------------------------------------------------
// 256x256-tile int8 GEMM, 8 waves (2x4), 128x64 per wave, BK=128.
// 8-phase-style schedule (T3+T4+T5): 4 phases/K-tile, raw s_barrier, counted
// vmcnt(4) at K-half boundaries (never 0 in steady state), setprio around the
// 16-MFMA clusters. LDS 128 KB = 2 dbuf x 2 K-half x (A 256x64 + B 256x64).
// LDS rows are 64 B = 4 chunks of 16 B; chunk c of row r stored at slot
// c ^ ((r>>1)&3)  (quarter-wave phase-conflict-free for b128 reads AND linear
// for the global_load_lds DMA; the inverse swizzle is applied to the per-lane
// GLOBAL source address - both-sides-or-neither rule).
// ---------------------------------------------------------------------------
#define AS1C (const __attribute__((address_space(1))) void*)
#define AS3C (__attribute__((address_space(3))) void*)
#define BAR() asm volatile("s_barrier" ::: "memory")
#define LGKM0() do { asm volatile("s_waitcnt lgkmcnt(0)" ::: "memory"); \
                     __builtin_amdgcn_sched_barrier(0); } while (0)
#define VMBAR(N) asm volatile("s_waitcnt vmcnt(" #N ")\ns_barrier" ::: "memory")

// stage A rows 0..255 (2 instrs/wave, 8 rows each x 8 waves x 2) of (d,kh)
#define STAGE_A2(d, kh, koff) do { \
    unsigned char* _p = smem + (((d) * 2 + (kh)) << 15) + wave * 1024; \
    __builtin_amdgcn_global_load_lds(AS1C(aS0 + (koff)), AS3C(_p), 16, 0, 0); \
    __builtin_amdgcn_global_load_lds(AS1C(aS1 + (koff)), AS3C(_p + 8192), 16, 0, 0); \
} while (0)
#define STAGE_B2(d, kh, koff) do { \
    unsigned char* _p = smem + (((d) * 2 + (kh)) << 15) + 16384 + wave * 1024; \
    __builtin_amdgcn_global_load_lds(AS1C(bS0 + (koff)), AS3C(_p), 16, 0, 0); \
    __builtin_amdgcn_global_load_lds(AS1C(bS1 + (koff)), AS3C(_p + 8192), 16, 0, 0); \
} while (0)

#define MFMA_BLOCK(MB) do { \
    __builtin_amdgcn_s_setprio(1); \
    _Pragma("unroll") \
    for (int _m = 0; _m < 4; ++_m) { \
        _Pragma("unroll") \
        for (int _u = 0; _u < 4; ++_u) \
            acc[(MB) + _m][_u] = __builtin_amdgcn_mfma_i32_16x16x64_i8( \
                af[_m], bf[_u], acc[(MB) + _m][_u], 0, 0, 0); \
    } \
    __builtin_amdgcn_s_setprio(0); \
} while (0)

__global__ __launch_bounds__(512, 2)
void gemm_all(const unsigned char* __restrict__ postq, const unsigned char* __restrict__ brandq,
              const float* __restrict__ dvec,
              const float* __restrict__ inv_post, const float* __restrict__ inv_brand,
              float* __restrict__ sum_post, float* __restrict__ cnt_post,
              float* __restrict__ sum_brand, float* __restrict__ cnt_brand) {
    __shared__ __align__(16) unsigned char smem[2 * 2 * (BM + BN) * 64];   // 131072 B

    const int tid = threadIdx.x;
    const int wave = tid >> 6, lane = tid & 63;
    const int wr = wave >> 2, wc = wave & 3;     // 2 x 4 wave grid

    // XCD-bijective block swizzle (528 = 8 * 66)
    int idx = (int)((blockIdx.x & 7) * 66 + (blockIdx.x >> 3));

    const unsigned char *A, *B;
    const float *invA, *invB;
    float *srow, *scol, *crow, *ccol;
    int bm, bn;
    float iaScale;
    bool is_cross, do_cols;

    if (idx < NCROSS) {
        is_cross = true; do_cols = true;
        bm = (idx >> 4) * BM; bn = (idx & 15) * BN;
        A = postq; B = brandq;
        invA = inv_post; invB = inv_brand; iaScale = INVT;
        srow = sum_post; crow = cnt_post; scol = sum_brand; ccol = cnt_brand;
    } else {
        is_cross = false;
        idx -= NCROSS;
        const unsigned char* X; const float* invx; float* sacc;
        if (idx >= NTILES) { idx -= NTILES; X = brandq; invx = inv_brand; sacc = sum_brand; }
        else               {               X = postq;  invx = inv_post;  sacc = sum_post;  }
        int J = (int)((sqrtf(8.f * idx + 1.f) - 1.f) * 0.5f);
        while ((J + 1) * (J + 2) / 2 <= idx) ++J;
        while (J * (J + 1) / 2 > idx) --J;
        const int I = idx - J * (J + 1) / 2;
        bm = I * BM; bn = J * BN;
        A = X; B = X;
        invA = invx; invB = invx; iaScale = 0.8f * INVT;
        srow = sacc; scol = sacc; crow = nullptr; ccol = nullptr;
        do_cols = (I != J);
    }

    // ---- staging lane constants (inverse-swizzled global source, linear LDS) ----
    const int srowi = wave * 16 + (lane >> 2);               // row within 128-row group
    const int csw = (((lane & 3) ^ ((wave * 8 + (lane >> 3)) & 3))) * 16;
    const unsigned char* aS0 = A + (size_t)(bm + srowi) * GK + csw;        // rows 0-127
    const unsigned char* aS1 = aS0 + (size_t)128 * GK;                     // rows 128-255
    const unsigned char* bS0 = B + (size_t)(bn + srowi) * GK + csw;
    const unsigned char* bS1 = bS0 + (size_t)128 * GK;

    // ---- fragment-read lane constants (swizzled chunk, const across frag idx) ----
    const int lrow = lane & 15, kq = lane >> 4;
    const int aRow = wr * 128 + lrow;
    const int bRow = wc * 64 + lrow;
    const unsigned char* aLds = smem + aRow * 64 + ((kq ^ ((aRow >> 1) & 3)) * 16);
    const unsigned char* bLds = smem + 16384 + bRow * 64 + ((kq ^ ((bRow >> 1) & 3)) * 16);

    intx4 acc[8][4] = {};

    // prologue: stage tile 0 (kh0 then kh1), wait kh0 only (kh1 stays in flight)
    STAGE_A2(0, 0, 0); STAGE_B2(0, 0, 0);
    STAGE_A2(0, 1, 64); STAGE_B2(0, 1, 64);
    VMBAR(4);

    #pragma unroll 1
    for (int t = 0; t < NT; ++t) {
        const int d = t & 1, nd = d ^ 1;
        const int kn = (t + 1) * BK;
        const bool lastT = (t == NT - 1);
        const unsigned char* aH0 = aLds + ((d * 2 + 0) << 15);
        const unsigned char* bH0 = bLds + ((d * 2 + 0) << 15);
        const unsigned char* aH1 = aLds + ((d * 2 + 1) << 15);
        const unsigned char* bH1 = bLds + ((d * 2 + 1) << 15);
        intx4 af[4], bf[4];

        // ---- PH0: kh0, m-frags 0..3 ; prefetch next.kh0 A ----
        #pragma unroll
        for (int u = 0; u < 4; ++u) bf[u] = *(const intx4*)(bH0 + u * 1024);
        #pragma unroll
        for (int m = 0; m < 4; ++m) af[m] = *(const intx4*)(aH0 + m * 1024);
        if (!lastT) STAGE_A2(nd, 0, kn);
        BAR(); LGKM0();
        MFMA_BLOCK(0);
        BAR();

        // ---- PH1: kh0, m-frags 4..7 ; prefetch next.kh0 B ; kh1-ready wait ----
        #pragma unroll
        for (int m = 0; m < 4; ++m) af[m] = *(const intx4*)(aH0 + 4096 + m * 1024);
        if (!lastT) STAGE_B2(nd, 0, kn);
        BAR(); LGKM0();
        MFMA_BLOCK(4);
        if (!lastT) VMBAR(4); else VMBAR(0);

        // ---- PH2: kh1, m-frags 0..3 ; prefetch next.kh1 A ----
        #pragma unroll
        for (int u = 0; u < 4; ++u) bf[u] = *(const intx4*)(bH1 + u * 1024);
        #pragma unroll
        for (int m = 0; m < 4; ++m) af[m] = *(const intx4*)(aH1 + m * 1024);
        if (!lastT) STAGE_A2(nd, 1, kn + 64);
        BAR(); LGKM0();
        MFMA_BLOCK(0);
        BAR();

        // ---- PH3: kh1, m-frags 4..7 ; prefetch next.kh1 B ; next.kh0-ready wait ----
        #pragma unroll
        for (int m = 0; m < 4; ++m) af[m] = *(const intx4*)(aH1 + 4096 + m * 1024);
        if (!lastT) STAGE_B2(nd, 1, kn + 64);
        BAR(); LGKM0();
        MFMA_BLOCK(4);
        if (!lastT) VMBAR(4);
    }
    __syncthreads();   // full drain once; separates tile reads from epilogue red alias

    // ---- epilogue (C/D: col=lane&15, row=(lane>>4)*4+reg; shape-determined) ----
    const int cn = lane & 15, rq = lane >> 4;
    float ib_c[4], db_c[4];
    #pragma unroll
    for (int u = 0; u < 4; ++u) {
        const int gc = bn + wc * 64 + u * 16 + cn;
        ib_c[u] = invB[gc];
        db_c[u] = is_cross ? dvec[gc] : 0.f;
    }

    float csum[4] = {}, ccnt[4] = {};
    float my_rs[2] = {}, my_rc[2] = {};
    #pragma unroll
    for (int t8 = 0; t8 < 8; ++t8) {
        #pragma unroll
        for (int r = 0; r < 4; ++r) {
            const int rl = wr * 128 + t8 * 16 + rq * 4 + r;
            const int grow = bm + rl;
            const float ia = invA[grow] * iaScale;
            float v = 0.f, w = 0.f;
            if (is_cross) {
                const float da = dvec[grow];
                #pragma unroll
                for (int u = 0; u < 4; ++u) {
                    const float s = (float)acc[t8][u][r];   // exact int < 2^24
                    const int gcol = bn + wc * 64 + u * 16 + cn;
                    const bool diag = (grow == gcol);
                    float e = __expf(s * ia * ib_c[u]);
                    v += e;
                    csum[u] += e;
                    w += (!diag && s > da) ? 1.f : 0.f;
                    ccnt[u] += (!diag && s > db_c[u]) ? 1.f : 0.f;
                }
                w += __shfl_xor(w, 1); w += __shfl_xor(w, 2);
                w += __shfl_xor(w, 4); w += __shfl_xor(w, 8);
            } else {
                #pragma unroll
                for (int u = 0; u < 4; ++u) {
                    const float s = (float)acc[t8][u][r];
                    const int gcol = bn + wc * 64 + u * 16 + cn;
                    float e = (grow == gcol) ? 1.0f : __expf(s * ia * ib_c[u]);
                    v += e;
                    csum[u] += e;
                }
            }
            v += __shfl_xor(v, 1); v += __shfl_xor(v, 2);
            v += __shfl_xor(v, 4); v += __shfl_xor(v, 8);
            const int p = t8 * 4 + r;                // 0..31 row-slots, 16 lanes
            if (cn == (p & 15)) { my_rs[p >> 4] = v; my_rc[p >> 4] = w; }
        }
    }

    // reduction scratch aliases the (dead) tile LDS
    float (*redRS)[4] = (float(*)[4])(smem);             // 256 x 4 (wc)
    float (*redRC)[4] = (float(*)[4])(smem + 4096);
    float (*redCS)[2] = (float(*)[2])(smem + 8192);      // 256 x 2 (wr)
    float (*redCC)[2] = (float(*)[2])(smem + 10240);

    const int rlA = wr * 128 + (cn >> 2) * 16 + rq * 4 + (cn & 3);
    redRS[rlA][wc]      = my_rs[0];
    redRS[rlA + 64][wc] = my_rs[1];
    redRC[rlA][wc]      = my_rc[0];
    redRC[rlA + 64][wc] = my_rc[1];

    float my_cs = 0.f, my_cc = 0.f;
    #pragma unroll
    for (int u = 0; u < 4; ++u) {
        float v = csum[u];
        v += __shfl_xor(v, 16); v += __shfl_xor(v, 32);
        if (rq == u) my_cs = v;
        if (is_cross) {
            float w2 = ccnt[u];
            w2 += __shfl_xor(w2, 16); w2 += __shfl_xor(w2, 32);
            if (rq == u) my_cc = w2;
        }
    }
    const int clA = wc * 64 + rq * 16 + cn;
    redCS[clA][wr] = my_cs;
    redCC[clA][wr] = my_cc;
    __syncthreads();

    if (tid < 256) {
        atomicAdd(&srow[bm + tid],
                  redRS[tid][0] + redRS[tid][1] + redRS[tid][2] + redRS[tid][3]);
        if (is_cross)
            atomicAdd(&crow[bm + tid],
                      redRC[tid][0] + redRC[tid][1] + redRC[tid][2] + redRC[tid][3]);
    } else if (do_cols) {
        const int t2 = tid - 256;
        atomicAdd(&scol[bn + t2], redCS[t2][0] + redCS[t2][1]);
        if (is_cross) atomicAdd(&ccol[bn + t2], redCC[t2][0] + redCC[t2][1]);
    }
}

// Final per-row loss assembly + global sum
__global__ __launch_bounds__(256)
void final_loss(const float* __restrict__ sum_post, const float* __restrict__ cnt_post,
                const float* __restrict__ sum_brand, const float* __restrict__ cnt_brand,
                const float* __restrict__ dvec,
                const float* __restrict__ inv_post, const float* __restrict__ inv_brand,
                float* __restrict__ out) {
    const int i = blockIdx.x * 256 + threadIdx.x;
    float dl = dvec[i] * inv_post[i] * inv_brand[i] * INVT;
    float lp = logf(sum_post[i]);
    float lb = logf(sum_brand[i]);
    float rp = 1.0f / (4096.0f - cnt_post[i]) + 1.0f;
    float rb = 1.0f / (4096.0f - cnt_brand[i]) + 1.0f;
    float loss = 0.5f * (rb * (lb - dl) + rp * (lp - dl));
    #pragma unroll
    for (int off = 32; off > 0; off >>= 1) loss += __shfl_down(loss, off);
    __shared__ float sw[4];
    int wave = threadIdx.x >> 6, lane = threadIdx.x & 63;
    if (lane == 0) sw[wave] = loss;
    __syncthreads();
    if (threadIdx.x == 0) atomicAdd(out, sw[0] + sw[1] + sw[2] + sw[3]);
}

extern "C" void kernel_launch(void* const* d_in, const int* in_sizes, int n_in,
                              void* d_out, int out_size, void* d_ws, size_t ws_size,
                              hipStream_t stream) {
    const float* brand = (const float*)d_in[0];
    const float* post  = (const float*)d_in[1];
    float* out = (float*)d_out;

    char* ws = (char*)d_ws;
    unsigned char* postq  = (unsigned char*)ws;                          // 4 MB
    unsigned char* brandq = postq + (size_t)GN * GK;                     // 4 MB
    float* inv_post  = (float*)(brandq + (size_t)GN * GK);
    float* inv_brand = inv_post + GN;
    float* dvec      = inv_brand + GN;
    float* accs      = dvec + GN;        // [sum_post, sum_brand, cnt_post, cnt_brand]
    float* sum_post  = accs;
    float* sum_brand = accs + GN;
    float* cnt_post  = accs + 2 * GN;
    float* cnt_brand = accs + 3 * GN;

    prep_all<<<GN, 256, 0, stream>>>(brand, post, brandq, postq,
                                     inv_brand, inv_post, dvec, accs, out);
    gemm_all<<<NCROSS + 2 * NTILES, 512, 0, stream>>>(postq, brandq, dvec,
                                                      inv_post, inv_brand,
                                                      sum_post, cnt_post,
                                                      sum_brand, cnt_brand);
    final_loss<<<GN / 256, 256, 0, stream>>>(sum_post, cnt_post, sum_brand, cnt_brand,
                                             dvec, inv_post, inv_brand, out);
}